// Round 6
// baseline (311.422 us; speedup 1.0000x reference)
//
#include <hip/hip_runtime.h>

#define N 343        // 7*7*7 tokens per window
#define NP 352       // padded to 11 tiles of 32
#define DIM 128
#define HEADS 4
#define DH 32

typedef float  f32x16 __attribute__((ext_vector_type(16)));
typedef float  float4v __attribute__((ext_vector_type(4)));
typedef short  short8 __attribute__((ext_vector_type(8)));
typedef unsigned uint4v __attribute__((ext_vector_type(4)));
typedef unsigned uint2v __attribute__((ext_vector_type(2)));

#define MFMA __builtin_amdgcn_mfma_f32_32x32x16_bf16

// ---- gfx950 packed bf16 convert (RNE) and cross-half swap -----------------
static __device__ __forceinline__ unsigned cvtpk_bf16(float lo, float hi) {
  unsigned r;
  asm("v_cvt_pk_bf16_f32 %0, %1, %2" : "=v"(r) : "v"(lo), "v"(hi));
  return r;
}
static __device__ __forceinline__ void swap32(unsigned &a, unsigned &b) {
  // a' = [a.lo32lanes | b.lo32lanes], b' = [a.hi32lanes | b.hi32lanes]
  asm("v_permlane32_swap_b32 %0, %1" : "+v"(a), "+v"(b));
}
// native base-2 exponential (v_exp_f32 IS exp2 on CDNA)
static __device__ __forceinline__ float exp2v(float x) {
  float r;
  asm("v_exp_f32 %0, %1" : "=v"(r) : "v"(x));
  return r;
}
static __device__ __forceinline__ unsigned short bf16u(float a) {
  unsigned u = __builtin_bit_cast(unsigned, a);
  unsigned r = u + 0x7fffu + ((u >> 16) & 1u);
  return (unsigned short)(r >> 16);
}
// split (a,b) into packed bf16 hi + lo parts (hi: a->low16, b->high16)
static __device__ __forceinline__ void split2pk(float a, float b,
                                                unsigned &hi, unsigned &lo) {
  hi = cvtpk_bf16(a, b);
  float ra = a - __builtin_bit_cast(float, hi << 16);
  float rb = b - __builtin_bit_cast(float, hi & 0xffff0000u);
  lo = cvtpk_bf16(ra, rb);
}

// ---------------------------------------------------------------------------
// Kernel 1: bias gather pre-permuted into the 32x32 MFMA C-fragment order so
// phase 2 loads it as one f32x16 straight into the MFMA C operand.
// Row = (h, jt, half, i); 16 floats = r-ordered bias(j(r,half), i) * log2(e).
// j >= 343 -> -1.44e30 (masks pad keys).
// ---------------------------------------------------------------------------
__global__ __launch_bounds__(256) void bias_kernel(
    const float* __restrict__ table, const int* __restrict__ rel,
    float* __restrict__ prep) {
  int row = blockIdx.x * 256 + threadIdx.x;
  if (row >= HEADS * 11 * 2 * NP) return;
  int i = row % NP;
  int t = row / NP;
  int half = t & 1;
  int tj = t >> 1;
  int jt = tj % 11;
  int h = tj / 11;
  float* dst = prep + (size_t)row * 16;
#pragma unroll
  for (int r = 0; r < 16; ++r) {
    int j = jt * 32 + (r & 3) + ((r >> 2) << 3) + (half << 2);
    float v;
    if (j >= N) v = -1.44e30f;
    else if (i >= N) v = 0.f;
    else v = table[rel[i * N + j] * HEADS + h] * 1.4426950408889634f;
    dst[r] = v;
  }
}

// ---------------------------------------------------------------------------
// Phase-2 flash loop for one 32-row M-tile (Q held in registers).
// ---------------------------------------------------------------------------
static __device__ __forceinline__ void attend(
    int i0, uint4v qAu, uint4v qBu,
    const unsigned short* __restrict__ Kb, const unsigned short* __restrict__ Vt,
    const float* __restrict__ bp, float* __restrict__ outw,
    int l31, int half, int swz) {
  short8 q0 = __builtin_bit_cast(short8, qAu);
  short8 q1 = __builtin_bit_cast(short8, qBu);
  const float* bpi = bp + (size_t)(i0 + l31) * 16;

  f32x16 O;
#pragma unroll
  for (int r = 0; r < 16; ++r) O[r] = 0.f;
  float m_run = -3.0e38f, l_run = 0.f;

  f32x16 Tn = *(const f32x16*)(bpi);      // prefetch bias tile 0
  for (int jt = 0; jt < 11; ++jt) {
    f32x16 T = Tn;                        // bias IS the MFMA C-input
    if (jt < 10) Tn = *(const f32x16*)(bpi + (size_t)(jt + 1) * 11264);

    const int krow = (jt * 32 + l31) * 40;
    short8 ka0 = *(const short8*)&Kb[krow + ((half * 8) ^ swz)];
    short8 ka1 = *(const short8*)&Kb[krow + ((half * 8 + 16) ^ swz)];
    T = MFMA(ka0, q0, T, 0, 0, 0);
    T = MFMA(ka1, q1, T, 0, 0, 0);

    // per-lane max, tree depth 4 + cross-half
    float m0 = fmaxf(T[0], T[1]),   m1 = fmaxf(T[2], T[3]);
    float m2 = fmaxf(T[4], T[5]),   m3 = fmaxf(T[6], T[7]);
    float m4 = fmaxf(T[8], T[9]),   m5 = fmaxf(T[10], T[11]);
    float m6 = fmaxf(T[12], T[13]), m7 = fmaxf(T[14], T[15]);
    m0 = fmaxf(m0, m1); m2 = fmaxf(m2, m3);
    m4 = fmaxf(m4, m5); m6 = fmaxf(m6, m7);
    m0 = fmaxf(m0, m2); m4 = fmaxf(m4, m6);
    float pm = fmaxf(m0, m4);
    pm = fmaxf(pm, __shfl_xor(pm, 32, 64));

    if (__any(pm > m_run + 11.5f)) {      // deferred-max rescale (rare)
      float nm = fmaxf(m_run, pm);
      float f = exp2v(m_run - nm);
      l_run *= f;
      m_run = nm;
#pragma unroll
      for (int r = 0; r < 16; ++r) {
        int iD = (r & 3) + ((r >> 2) << 3) + (half << 2);
        O[r] *= __shfl(f, iD, 64);
      }
    }

    float p[16];
#pragma unroll
    for (int r = 0; r < 16; ++r) p[r] = exp2v(T[r] - m_run);
    float s0 = (p[0] + p[1]) + (p[2] + p[3]);
    float s1 = (p[4] + p[5]) + (p[6] + p[7]);
    float s2 = (p[8] + p[9]) + (p[10] + p[11]);
    float s3 = (p[12] + p[13]) + (p[14] + p[15]);
    float ps = (s0 + s1) + (s2 + s3);
    l_run += ps + __shfl_xor(ps, 32, 64);

    // P -> PV A-fragment: 8 cvt_pk + 4 permlane32_swap
    unsigned k0 = cvtpk_bf16(p[0], p[1]),   k1 = cvtpk_bf16(p[2], p[3]);
    unsigned k2 = cvtpk_bf16(p[4], p[5]),   k3 = cvtpk_bf16(p[6], p[7]);
    unsigned k4 = cvtpk_bf16(p[8], p[9]),   k5 = cvtpk_bf16(p[10], p[11]);
    unsigned k6 = cvtpk_bf16(p[12], p[13]), k7 = cvtpk_bf16(p[14], p[15]);
    swap32(k0, k2); swap32(k1, k3); swap32(k4, k6); swap32(k5, k7);
    uint4v u1 = {k0, k1, k2, k3};
    uint4v u2 = {k4, k5, k6, k7};
    short8 pa1 = __builtin_bit_cast(short8, u1);
    short8 pa2 = __builtin_bit_cast(short8, u2);

    const int vrow = l31 * 368 + jt * 32 + half * 8;
    short8 vb1 = *(const short8*)&Vt[vrow];
    short8 vb2 = *(const short8*)&Vt[vrow + 16];
    O = MFMA(pa1, vb1, O, 0, 0, 0);
    O = MFMA(pa2, vb2, O, 0, 0, 0);
  }

  float inv = 1.0f / l_run;
#pragma unroll
  for (int r = 0; r < 16; ++r) {
    int iD = (r & 3) + ((r >> 2) << 3) + (half << 2);
    float invr = __shfl(inv, iD, 64);
    int i = i0 + iD;
    if (i < N) outw[(size_t)i * DIM + l31] = O[r] * invr;
  }
}

// ---------------------------------------------------------------------------
// Kernel 2: fused QKV projection + attention. One block per (window, head),
// 384 threads = 6 waves, 51712 B LDS -> 2 blocks/CU (12 waves/CU).
// Phase 1 (k-chunks of 16): hi/lo-split bf16 MFMA. Q is computed TRANSPOSED
// (mfma(W,X)) so its C-fragment converts in-register to the phase-2
// B-fragment via cvt_pk+permlane32_swap -> Q never touches LDS.
// K tile swizzled ([row][col^((row>>3)&3)<<3]) -> conflict-free ds_read_b128.
// ---------------------------------------------------------------------------
__global__ __launch_bounds__(384, 3) void attn_kernel(
    const float* __restrict__ x, const float* __restrict__ wqkv,
    const float* __restrict__ prep, float* __restrict__ out) {
  const int b = blockIdx.x;
  const int sw = (b & 7) * ((int)gridDim.x >> 3) + (b >> 3);  // XCD swizzle
  const int h = sw & 3;
  const int w = sw >> 2;
  const int tid = threadIdx.x;
  const int lane = tid & 63;
  const int wv = tid >> 6;        // 0..5
  const int l31 = lane & 31;
  const int half = lane >> 5;

  __shared__ __align__(16) unsigned short lds[25856];   // 51712 B
  unsigned short* Xh = lds;             // [352][24]  (phase 1)
  unsigned short* Xl = lds + 8448;      // [352][24]
  unsigned short* Wh = lds + 16896;     // [96][24]
  unsigned short* Wl = lds + 19200;     // [96][24]
  unsigned short* Kb = lds;             // [352][40]  (phase 2, aliased)
  unsigned short* Vt = lds + 14080;     // [32][368]

  const float* xw = x + (size_t)w * (N * DIM);
  const int mt0 = wv;
  const bool two = (wv < 5);
  const int mt1 = two ? wv + 6 : 5;     // clamped; guarded by `two`

  f32x16 a0, a1, a2, a3, a4, a5;
#pragma unroll
  for (int r = 0; r < 16; ++r) {
    a0[r] = 0.f; a1[r] = 0.f; a2[r] = 0.f;
    a3[r] = 0.f; a4[r] = 0.f; a5[r] = 0.f;
  }

  // ---------------- Phase 1: QKV projection, k-chunks of 16 ----------------
  for (int kc = 0; kc < 8; ++kc) {
    __syncthreads();
    // stage X[:, kc*16..+16) as hi/lo bf16 -> [352][24] (1408 float4-groups)
#pragma unroll
    for (int p = 0; p < 4; ++p) {
      int idx = tid + p * 384;
      if (idx < 1408) {
        int row = idx >> 2, g = (idx & 3) << 2;
        float4v v = {0.f, 0.f, 0.f, 0.f};
        if (row < N) v = *(const float4v*)(xw + row * DIM + kc * 16 + g);
        unsigned h0, l0, h1, l1;
        split2pk(v[0], v[1], h0, l0);
        split2pk(v[2], v[3], h1, l1);
        uint2v hv = {h0, h1}, lv = {l0, l1};
        *(uint2v*)&Xh[row * 24 + g] = hv;
        *(uint2v*)&Xl[row * 24 + g] = lv;
      }
    }
    // stage W slice transposed [c 0..95][k 0..15] (exactly 384 groups)
    {
      int c = tid % 96, kg = (tid / 96) << 2;
      int col = ((c >> 5) << 7) + h * DH + (c & 31);
      const float* wp = wqkv + (size_t)(kc * 16 + kg) * (3 * DIM) + col;
      unsigned h0, l0, h1, l1;
      split2pk(wp[0], wp[384], h0, l0);
      split2pk(wp[768], wp[1152], h1, l1);
      uint2v hv = {h0, h1}, lv = {l0, l1};
      *(uint2v*)&Wh[c * 24 + kg] = hv;
      *(uint2v*)&Wl[c * 24 + kg] = lv;
    }
    __syncthreads();

    const int xb0 = (mt0 * 32 + l31) * 24 + half * 8;
    const int xb1 = (mt1 * 32 + l31) * 24 + half * 8;
    short8 xh0 = *(const short8*)&Xh[xb0];
    short8 xl0 = *(const short8*)&Xl[xb0];
    short8 xh1 = {0, 0, 0, 0, 0, 0, 0, 0};
    short8 xl1 = {0, 0, 0, 0, 0, 0, 0, 0};
    if (two) {
      xh1 = *(const short8*)&Xh[xb1];
      xl1 = *(const short8*)&Xl[xb1];
    }
    {  // Q tiles: TRANSPOSED -> A = Wq, B = X
      int wb = l31 * 24 + half * 8;
      short8 wh8 = *(const short8*)&Wh[wb];
      short8 wl8 = *(const short8*)&Wl[wb];
      a0 = MFMA(wh8, xh0, a0, 0, 0, 0);
      a0 = MFMA(wh8, xl0, a0, 0, 0, 0);
      a0 = MFMA(wl8, xh0, a0, 0, 0, 0);
      if (two) {
        a1 = MFMA(wh8, xh1, a1, 0, 0, 0);
        a1 = MFMA(wh8, xl1, a1, 0, 0, 0);
        a1 = MFMA(wl8, xh1, a1, 0, 0, 0);
      }
    }
    {  // K tiles: A = X, B = Wk
      int wb = (32 + l31) * 24 + half * 8;
      short8 wh8 = *(const short8*)&Wh[wb];
      short8 wl8 = *(const short8*)&Wl[wb];
      a2 = MFMA(xh0, wh8, a2, 0, 0, 0);
      a2 = MFMA(xl0, wh8, a2, 0, 0, 0);
      a2 = MFMA(xh0, wl8, a2, 0, 0, 0);
      if (two) {
        a3 = MFMA(xh1, wh8, a3, 0, 0, 0);
        a3 = MFMA(xl1, wh8, a3, 0, 0, 0);
        a3 = MFMA(xh1, wl8, a3, 0, 0, 0);
      }
    }
    {  // V tiles: A = X, B = Wv
      int wb = (64 + l31) * 24 + half * 8;
      short8 wh8 = *(const short8*)&Wh[wb];
      short8 wl8 = *(const short8*)&Wl[wb];
      a4 = MFMA(xh0, wh8, a4, 0, 0, 0);
      a4 = MFMA(xl0, wh8, a4, 0, 0, 0);
      a4 = MFMA(xh0, wl8, a4, 0, 0, 0);
      if (two) {
        a5 = MFMA(xh1, wh8, a5, 0, 0, 0);
        a5 = MFMA(xl1, wh8, a5, 0, 0, 0);
        a5 = MFMA(xh1, wl8, a5, 0, 0, 0);
      }
    }
  }

  __syncthreads();  // all X/W reads done; safe to overwrite with K/V

  // ---- Q^T acc -> phase-2 B-fragment, fully in registers ----
  const float QS = 0.17677669529663687f * 1.4426950408889634f;  // /sqrt(32)*log2e
  uint4v qA0, qB0;
  uint4v qA1 = {0, 0, 0, 0}, qB1 = {0, 0, 0, 0};
  {
    unsigned g0 = cvtpk_bf16(a0[0] * QS, a0[1] * QS);
    unsigned g1 = cvtpk_bf16(a0[2] * QS, a0[3] * QS);
    unsigned g2 = cvtpk_bf16(a0[4] * QS, a0[5] * QS);
    unsigned g3 = cvtpk_bf16(a0[6] * QS, a0[7] * QS);
    unsigned g4 = cvtpk_bf16(a0[8] * QS, a0[9] * QS);
    unsigned g5 = cvtpk_bf16(a0[10] * QS, a0[11] * QS);
    unsigned g6 = cvtpk_bf16(a0[12] * QS, a0[13] * QS);
    unsigned g7 = cvtpk_bf16(a0[14] * QS, a0[15] * QS);
    swap32(g0, g2); swap32(g1, g3); swap32(g4, g6); swap32(g5, g7);
    qA0[0] = g0; qA0[1] = g1; qA0[2] = g2; qA0[3] = g3;
    qB0[0] = g4; qB0[1] = g5; qB0[2] = g6; qB0[3] = g7;
  }
  if (two) {
    unsigned g0 = cvtpk_bf16(a1[0] * QS, a1[1] * QS);
    unsigned g1 = cvtpk_bf16(a1[2] * QS, a1[3] * QS);
    unsigned g2 = cvtpk_bf16(a1[4] * QS, a1[5] * QS);
    unsigned g3 = cvtpk_bf16(a1[6] * QS, a1[7] * QS);
    unsigned g4 = cvtpk_bf16(a1[8] * QS, a1[9] * QS);
    unsigned g5 = cvtpk_bf16(a1[10] * QS, a1[11] * QS);
    unsigned g6 = cvtpk_bf16(a1[12] * QS, a1[13] * QS);
    unsigned g7 = cvtpk_bf16(a1[14] * QS, a1[15] * QS);
    swap32(g0, g2); swap32(g1, g3); swap32(g4, g6); swap32(g5, g7);
    qA1[0] = g0; qA1[1] = g1; qA1[2] = g2; qA1[3] = g3;
    qB1[0] = g4; qB1[1] = g5; qB1[2] = g6; qB1[3] = g7;
  }

  // ---- K -> LDS (XOR-swizzled), V -> LDS (transposed) ----
#pragma unroll
  for (int r = 0; r < 16; ++r) {
    int iD = (r & 3) + ((r >> 2) << 3) + (half << 2);
    int cs = l31 ^ ((r >> 2) << 3);
    Kb[(mt0 * 32 + iD) * 40 + cs] = bf16u(a2[r]);
    if (two) Kb[(mt1 * 32 + iD) * 40 + cs] = bf16u(a3[r]);
  }
#pragma unroll
  for (int r = 0; r < 16; r += 2) {
    int j0 = (r & 3) + ((r >> 2) << 3) + (half << 2);
    *(unsigned*)&Vt[l31 * 368 + mt0 * 32 + j0] = cvtpk_bf16(a4[r], a4[r + 1]);
    if (two)
      *(unsigned*)&Vt[l31 * 368 + mt1 * 32 + j0] = cvtpk_bf16(a5[r], a5[r + 1]);
  }
  __syncthreads();

  // ---------------- Phase 2: attention ----------------
  const float* bp = prep + ((size_t)(h * 22 + half) * NP) * 16;
  float* outw = out + (size_t)w * N * DIM + h * DH;
  const int swz = ((l31 >> 3) & 3) << 3;

  attend(mt0 * 32, qA0, qB0, Kb, Vt, bp, outw, l31, half, swz);
  if (two) attend(mt1 * 32, qA1, qB1, Kb, Vt, bp, outw, l31, half, swz);
}

// ---------------------------------------------------------------------------
// Kernel 3: out-projection, in-place on d_out, hi/lo split MFMA.
// One block per window, 512 threads (8 waves). Tiles: 11(M) x 4(N).
// ---------------------------------------------------------------------------
__global__ __launch_bounds__(512, 2) void proj_kernel(
    const float* __restrict__ wout, float* __restrict__ out) {
  const int w = blockIdx.x;
  const int tid = threadIdx.x;
  const int lane = tid & 63, wv = tid >> 6, l31 = lane & 31, half = lane >> 5;
  __shared__ __align__(16) char smem[76800];
  unsigned short* Oh = (unsigned short*)smem;             // [352][40]
  unsigned short* Ol = (unsigned short*)(smem + 28160);
  unsigned short* W2h = (unsigned short*)(smem + 56320);  // [128][40]
  unsigned short* W2l = (unsigned short*)(smem + 66560);
  float* ow = out + (size_t)w * N * DIM;

  f32x16 acc[6];
#pragma unroll
  for (int s = 0; s < 6; ++s)
#pragma unroll
    for (int r = 0; r < 16; ++r) acc[s][r] = 0.f;

  for (int kc = 0; kc < 4; ++kc) {
    __syncthreads();
#pragma unroll
    for (int p = 0; p < 11; ++p) {
      int idx = tid + p * 512;
      int row = idx >> 4, cp = (idx & 15) << 1;
      float a = 0.f, bb = 0.f;
      if (row < N) { const float* g = ow + row * DIM + kc * 32 + cp; a = g[0]; bb = g[1]; }
      unsigned hi, lo; split2pk(a, bb, hi, lo);
      *(unsigned*)&Oh[row * 40 + cp] = hi;
      *(unsigned*)&Ol[row * 40 + cp] = lo;
    }
#pragma unroll
    for (int p = 0; p < 8; ++p) {
      int idx = tid + p * 512;
      int k = idx >> 7, n = idx & 127;
      float v = wout[(size_t)(kc * 32 + k) * DIM + n];
      unsigned short hv = bf16u(v);
      W2h[n * 40 + k] = hv;
      W2l[n * 40 + k] = bf16u(v - __builtin_bit_cast(float, (unsigned)hv << 16));
    }
    __syncthreads();
#pragma unroll
    for (int s = 0; s < 6; ++s) {
      int id = wv + (s << 3);
      if (id < 44) {
        int mt5 = id >> 2, nt = id & 3;
        int rb = (mt5 * 32 + l31) * 40;
#pragma unroll
        for (int kk = 0; kk < 2; ++kk) {
          short8 ah = *(const short8*)&Oh[rb + kk * 16 + half * 8];
          short8 al = *(const short8*)&Ol[rb + kk * 16 + half * 8];
          int wb = (nt * 32 + l31) * 40 + kk * 16 + half * 8;
          short8 bh = *(const short8*)&W2h[wb];
          short8 bl = *(const short8*)&W2l[wb];
          acc[s] = MFMA(ah, bh, acc[s], 0, 0, 0);
          acc[s] = MFMA(ah, bl, acc[s], 0, 0, 0);
          acc[s] = MFMA(al, bh, acc[s], 0, 0, 0);
        }
      }
    }
  }
#pragma unroll
  for (int s = 0; s < 6; ++s) {
    int id = wv + (s << 3);
    if (id < 44) {
      int mt5 = id >> 2, nt = id & 3;
#pragma unroll
      for (int r = 0; r < 16; ++r) {
        int iD = (r & 3) + ((r >> 2) << 3) + (half << 2);
        int i = mt5 * 32 + iD;
        if (i < N) ow[(size_t)i * DIM + nt * 32 + l31] = acc[s][r];
      }
    }
  }
}

// ---------------------------------------------------------------------------
extern "C" void kernel_launch(void* const* d_in, const int* in_sizes, int n_in,
                              void* d_out, int out_size, void* d_ws, size_t ws_size,
                              hipStream_t stream) {
  const float* x     = (const float*)d_in[0];
  const float* wqkv  = (const float*)d_in[1];
  const float* wout  = (const float*)d_in[2];
  const float* table = (const float*)d_in[3];
  const int*   rel   = (const int*)d_in[4];
  float* out  = (float*)d_out;
  float* prep = (float*)d_ws;  // 4*11*2*352*16*4 B = 1.98 MB

  const int B = in_sizes[0] / (N * DIM);  // 512 windows
  const int rows = HEADS * 11 * 2 * NP;   // 30976

  bias_kernel<<<(rows + 255) / 256, 256, 0, stream>>>(table, rel, prep);
  attn_kernel<<<HEADS * B, 384, 0, stream>>>(x, wqkv, prep, out);
  proj_kernel<<<B, 512, 0, stream>>>(wout, out);
}

// Round 8
// 232.190 us; speedup vs baseline: 1.3412x; 1.3412x over previous
//
#include <hip/hip_runtime.h>

#define N 343        // 7*7*7 tokens per window
#define NP 352       // padded to 11 tiles of 32
#define DIM 128
#define HEADS 4
#define DH 32

typedef float  f32x16 __attribute__((ext_vector_type(16)));
typedef float  float4v __attribute__((ext_vector_type(4)));
typedef short  short8 __attribute__((ext_vector_type(8)));
typedef unsigned uint4v __attribute__((ext_vector_type(4)));
typedef unsigned uint2v __attribute__((ext_vector_type(2)));

#define MFMA __builtin_amdgcn_mfma_f32_32x32x16_bf16

// ---- gfx950 packed bf16 convert (RNE) and cross-half swap -----------------
static __device__ __forceinline__ unsigned cvtpk_bf16(float lo, float hi) {
  unsigned r;
  asm("v_cvt_pk_bf16_f32 %0, %1, %2" : "=v"(r) : "v"(lo), "v"(hi));
  return r;
}
static __device__ __forceinline__ void swap32(unsigned &a, unsigned &b) {
  asm("v_permlane32_swap_b32 %0, %1" : "+v"(a), "+v"(b));
}
// native base-2 exponential (v_exp_f32 IS exp2 on CDNA)
static __device__ __forceinline__ float exp2v(float x) {
  float r;
  asm("v_exp_f32 %0, %1" : "=v"(r) : "v"(x));
  return r;
}
static __device__ __forceinline__ unsigned short bf16u(float a) {
  unsigned u = __builtin_bit_cast(unsigned, a);
  unsigned r = u + 0x7fffu + ((u >> 16) & 1u);
  return (unsigned short)(r >> 16);
}
static __device__ __forceinline__ void split2pk(float a, float b,
                                                unsigned &hi, unsigned &lo) {
  hi = cvtpk_bf16(a, b);
  float ra = a - __builtin_bit_cast(float, hi << 16);
  float rb = b - __builtin_bit_cast(float, hi & 0xffff0000u);
  lo = cvtpk_bf16(ra, rb);
}

// ---------------------------------------------------------------------------
// Kernel 1: bias gather pre-permuted into the 32x32 MFMA C-fragment order.
// ---------------------------------------------------------------------------
__global__ __launch_bounds__(256) void bias_kernel(
    const float* __restrict__ table, const int* __restrict__ rel,
    float* __restrict__ prep) {
  int row = blockIdx.x * 256 + threadIdx.x;
  if (row >= HEADS * 11 * 2 * NP) return;
  int i = row % NP;
  int t = row / NP;
  int half = t & 1;
  int tj = t >> 1;
  int jt = tj % 11;
  int h = tj / 11;
  float* dst = prep + (size_t)row * 16;
#pragma unroll
  for (int r = 0; r < 16; ++r) {
    int j = jt * 32 + (r & 3) + ((r >> 2) << 3) + (half << 2);
    float v;
    if (j >= N) v = -1.44e30f;
    else if (i >= N) v = 0.f;
    else v = table[rel[i * N + j] * HEADS + h] * 1.4426950408889634f;
    dst[r] = v;
  }
}

// ---------------------------------------------------------------------------
// Phase-2 flash loop for one 32-row M-tile (Q held in registers).
// Kb: [352][40] col-swizzled by (row&24). Vt: [32][352] token-swizzled by
// (d&24) within each 32-token tile.
// ---------------------------------------------------------------------------
static __device__ __forceinline__ void attend(
    int i0, uint4v qAu, uint4v qBu,
    const unsigned short* __restrict__ Kb, const unsigned short* __restrict__ Vt,
    const float* __restrict__ bp, float* __restrict__ outw,
    int l31, int half, int swz) {
  short8 q0 = __builtin_bit_cast(short8, qAu);
  short8 q1 = __builtin_bit_cast(short8, qBu);
  const float* bpi = bp + (size_t)(i0 + l31) * 16;

  f32x16 O;
#pragma unroll
  for (int r = 0; r < 16; ++r) O[r] = 0.f;
  float m_run = -3.0e38f, l_run = 0.f;

  f32x16 Tn = *(const f32x16*)(bpi);      // prefetch bias tile 0
  for (int jt = 0; jt < 11; ++jt) {
    f32x16 T = Tn;                        // bias IS the MFMA C-input
    if (jt < 10) Tn = *(const f32x16*)(bpi + (size_t)(jt + 1) * 11264);

    const int krow = (jt * 32 + l31) * 40;
    short8 ka0 = *(const short8*)&Kb[krow + ((half * 8) ^ swz)];
    short8 ka1 = *(const short8*)&Kb[krow + ((half * 8 + 16) ^ swz)];
    T = MFMA(ka0, q0, T, 0, 0, 0);
    T = MFMA(ka1, q1, T, 0, 0, 0);

    float m0 = fmaxf(T[0], T[1]),   m1 = fmaxf(T[2], T[3]);
    float m2 = fmaxf(T[4], T[5]),   m3 = fmaxf(T[6], T[7]);
    float m4 = fmaxf(T[8], T[9]),   m5 = fmaxf(T[10], T[11]);
    float m6 = fmaxf(T[12], T[13]), m7 = fmaxf(T[14], T[15]);
    m0 = fmaxf(m0, m1); m2 = fmaxf(m2, m3);
    m4 = fmaxf(m4, m5); m6 = fmaxf(m6, m7);
    m0 = fmaxf(m0, m2); m4 = fmaxf(m4, m6);
    float pm = fmaxf(m0, m4);
    pm = fmaxf(pm, __shfl_xor(pm, 32, 64));

    if (__any(pm > m_run + 11.5f)) {      // deferred-max rescale (rare)
      float nm = fmaxf(m_run, pm);
      float f = exp2v(m_run - nm);
      l_run *= f;
      m_run = nm;
#pragma unroll
      for (int r = 0; r < 16; ++r) {
        int iD = (r & 3) + ((r >> 2) << 3) + (half << 2);
        O[r] *= __shfl(f, iD, 64);
      }
    }

    float p[16];
#pragma unroll
    for (int r = 0; r < 16; ++r) p[r] = exp2v(T[r] - m_run);
    float s0 = (p[0] + p[1]) + (p[2] + p[3]);
    float s1 = (p[4] + p[5]) + (p[6] + p[7]);
    float s2 = (p[8] + p[9]) + (p[10] + p[11]);
    float s3 = (p[12] + p[13]) + (p[14] + p[15]);
    float ps = (s0 + s1) + (s2 + s3);
    l_run += ps + __shfl_xor(ps, 32, 64);

    unsigned k0 = cvtpk_bf16(p[0], p[1]),   k1 = cvtpk_bf16(p[2], p[3]);
    unsigned k2 = cvtpk_bf16(p[4], p[5]),   k3 = cvtpk_bf16(p[6], p[7]);
    unsigned k4 = cvtpk_bf16(p[8], p[9]),   k5 = cvtpk_bf16(p[10], p[11]);
    unsigned k6 = cvtpk_bf16(p[12], p[13]), k7 = cvtpk_bf16(p[14], p[15]);
    swap32(k0, k2); swap32(k1, k3); swap32(k4, k6); swap32(k5, k7);
    uint4v u1 = {k0, k1, k2, k3};
    uint4v u2 = {k4, k5, k6, k7};
    short8 pa1 = __builtin_bit_cast(short8, u1);
    short8 pa2 = __builtin_bit_cast(short8, u2);

    const int vrow = l31 * 352 + jt * 32;
    short8 vb1 = *(const short8*)&Vt[vrow + ((half * 8) ^ swz)];
    short8 vb2 = *(const short8*)&Vt[vrow + ((half * 8 + 16) ^ swz)];
    O = MFMA(pa1, vb1, O, 0, 0, 0);
    O = MFMA(pa2, vb2, O, 0, 0, 0);
  }

  float inv = 1.0f / l_run;
#pragma unroll
  for (int r = 0; r < 16; ++r) {
    int iD = (r & 3) + ((r >> 2) << 3) + (half << 2);
    float invr = __shfl(inv, iD, 64);
    int i = i0 + iD;
    if (i < N) outw[(size_t)i * DIM + l31] = O[r] * invr;
  }
}

// ---------------------------------------------------------------------------
// Kernel 2: fused QKV projection + attention. One block per (window, head),
// 768 threads = 12 waves. ONE M-tile per wave -> 3 f32x16 accumulators
// (48 AGPR) -> ~130 total regs/wave -> 12 waves/CU resident (3/SIMD).
// Wave 11 is a staging helper.
// ---------------------------------------------------------------------------
__global__ __launch_bounds__(768, 3) void attn_kernel(
    const float* __restrict__ x, const float* __restrict__ wqkv,
    const float* __restrict__ prep, float* __restrict__ out) {
  const int b = blockIdx.x;
  const int sw = (b & 7) * ((int)gridDim.x >> 3) + (b >> 3);  // XCD swizzle
  const int h = sw & 3;
  const int w = sw >> 2;
  const int tid = threadIdx.x;
  const int lane = tid & 63;
  const int wv = tid >> 6;        // 0..11
  const int l31 = lane & 31;
  const int half = lane >> 5;

  __shared__ __align__(16) unsigned short lds[25344];   // 50688 B
  unsigned short* Xh = lds;             // [352][24]  (phase 1)
  unsigned short* Xl = lds + 8448;      // [352][24]
  unsigned short* Wh = lds + 16896;     // [96][24]
  unsigned short* Wl = lds + 19200;     // [96][24]
  unsigned short* Kb = lds;             // [352][40]  (phase 2, aliased)
  unsigned short* Vt = lds + 14080;     // [32][352]

  const float* xw = x + (size_t)w * (N * DIM);
  const int xsw = ((l31 >> 3) & 1) << 3;   // 1-bit swizzle for X/W frag reads
  const bool act = (wv < 11);

  f32x16 aQ, aK, aV;
#pragma unroll
  for (int r = 0; r < 16; ++r) { aQ[r] = 0.f; aK[r] = 0.f; aV[r] = 0.f; }

  // ---------------- Phase 1: QKV projection, k-chunks of 16 ----------------
  for (int kc = 0; kc < 8; ++kc) {
    __syncthreads();
    // stage X[:, kc*16..+16) as hi/lo bf16 -> [352][24] (1408 quad-groups)
#pragma unroll
    for (int p = 0; p < 2; ++p) {
      int idx = tid + p * 768;
      if (idx < 1408) {
        int row = idx >> 2, g = (idx & 3) << 2;
        float4v v = {0.f, 0.f, 0.f, 0.f};
        if (row < N) v = *(const float4v*)(xw + row * DIM + kc * 16 + g);
        unsigned h0, l0, h1, l1;
        split2pk(v[0], v[1], h0, l0);
        split2pk(v[2], v[3], h1, l1);
        uint2v hv = {h0, h1}, lv = {l0, l1};
        int gs = g ^ (((row >> 3) & 1) << 3);
        *(uint2v*)&Xh[row * 24 + gs] = hv;
        *(uint2v*)&Xl[row * 24 + gs] = lv;
      }
    }
    // stage W slice transposed [c 0..95][k 0..15] (384 quad-jobs)
    if (tid < 384) {
      int c = tid % 96, kg = (tid / 96) << 2;
      int col = ((c >> 5) << 7) + h * DH + (c & 31);
      const float* wp = wqkv + (size_t)(kc * 16 + kg) * (3 * DIM) + col;
      unsigned h0, l0, h1, l1;
      split2pk(wp[0], wp[384], h0, l0);
      split2pk(wp[768], wp[1152], h1, l1);
      uint2v hv = {h0, h1}, lv = {l0, l1};
      int kgs = kg ^ (((c >> 3) & 1) << 3);
      *(uint2v*)&Wh[c * 24 + kgs] = hv;
      *(uint2v*)&Wl[c * 24 + kgs] = lv;
    }
    __syncthreads();

    if (act) {
      const int fo = (half * 8) ^ xsw;
      const int xb = (wv * 32 + l31) * 24 + fo;
      short8 xh = *(const short8*)&Xh[xb];
      short8 xl = *(const short8*)&Xl[xb];
      {  // Q: TRANSPOSED -> A = Wq, B = X
        int wb = l31 * 24 + fo;
        short8 wh8 = *(const short8*)&Wh[wb];
        short8 wl8 = *(const short8*)&Wl[wb];
        aQ = MFMA(wh8, xh, aQ, 0, 0, 0);
        aQ = MFMA(wh8, xl, aQ, 0, 0, 0);
        aQ = MFMA(wl8, xh, aQ, 0, 0, 0);
      }
      {  // K: A = X, B = Wk
        int wb = (32 + l31) * 24 + fo;
        short8 wh8 = *(const short8*)&Wh[wb];
        short8 wl8 = *(const short8*)&Wl[wb];
        aK = MFMA(xh, wh8, aK, 0, 0, 0);
        aK = MFMA(xl, wh8, aK, 0, 0, 0);
        aK = MFMA(xh, wl8, aK, 0, 0, 0);
      }
      {  // V: A = X, B = Wv
        int wb = (64 + l31) * 24 + fo;
        short8 wh8 = *(const short8*)&Wh[wb];
        short8 wl8 = *(const short8*)&Wl[wb];
        aV = MFMA(xh, wh8, aV, 0, 0, 0);
        aV = MFMA(xl, wh8, aV, 0, 0, 0);
        aV = MFMA(xh, wl8, aV, 0, 0, 0);
      }
    }
  }

  __syncthreads();  // all X/W reads done; safe to overwrite with K/V

  // ---- Q^T acc -> phase-2 B-fragment, fully in registers ----
  const float QS = 0.17677669529663687f * 1.4426950408889634f;  // /sqrt(32)*log2e
  uint4v qA = {0, 0, 0, 0}, qB = {0, 0, 0, 0};
  const int swz = ((l31 >> 3) & 3) << 3;
  if (act) {
    unsigned g0 = cvtpk_bf16(aQ[0] * QS, aQ[1] * QS);
    unsigned g1 = cvtpk_bf16(aQ[2] * QS, aQ[3] * QS);
    unsigned g2 = cvtpk_bf16(aQ[4] * QS, aQ[5] * QS);
    unsigned g3 = cvtpk_bf16(aQ[6] * QS, aQ[7] * QS);
    unsigned g4 = cvtpk_bf16(aQ[8] * QS, aQ[9] * QS);
    unsigned g5 = cvtpk_bf16(aQ[10] * QS, aQ[11] * QS);
    unsigned g6 = cvtpk_bf16(aQ[12] * QS, aQ[13] * QS);
    unsigned g7 = cvtpk_bf16(aQ[14] * QS, aQ[15] * QS);
    swap32(g0, g2); swap32(g1, g3); swap32(g4, g6); swap32(g5, g7);
    qA[0] = g0; qA[1] = g1; qA[2] = g2; qA[3] = g3;
    qB[0] = g4; qB[1] = g5; qB[2] = g6; qB[3] = g7;

    // K -> LDS (2-bit XOR col swizzle)
#pragma unroll
    for (int r = 0; r < 16; ++r) {
      int iD = (r & 3) + ((r >> 2) << 3) + (half << 2);
      int cs = l31 ^ ((r >> 2) << 3);
      Kb[(wv * 32 + iD) * 40 + cs] = bf16u(aK[r]);
    }
    // V -> LDS transposed, stride 352, 2-bit XOR token swizzle within tile
#pragma unroll
    for (int r = 0; r < 16; r += 2) {
      int j0 = (r & 3) + ((r >> 2) << 3) + (half << 2);
      *(unsigned*)&Vt[l31 * 352 + wv * 32 + (j0 ^ swz)] =
          cvtpk_bf16(aV[r], aV[r + 1]);
    }
  }
  __syncthreads();

  // ---------------- Phase 2: attention ----------------
  if (act) {
    const float* bp = prep + ((size_t)(h * 22 + half) * NP) * 16;
    float* outw = out + (size_t)w * N * DIM + h * DH;
    attend(wv * 32, qA, qB, Kb, Vt, bp, outw, l31, half, swz);
  }
}

// ---------------------------------------------------------------------------
// Kernel 3: out-projection, in-place on d_out, hi/lo split MFMA.
// One block per window, 768 threads (12 waves). Wave wv<=10 owns M-tile wv,
// all 4 N-tiles (acc[4] = 64 AGPR -> 3 waves/SIMD).
// ---------------------------------------------------------------------------
__global__ __launch_bounds__(768, 3) void proj_kernel(
    const float* __restrict__ wout, float* __restrict__ out) {
  const int w = blockIdx.x;
  const int tid = threadIdx.x;
  const int lane = tid & 63, wv = tid >> 6, l31 = lane & 31, half = lane >> 5;
  __shared__ __align__(16) unsigned short lds[38400];     // 76800 B
  unsigned short* Oh = lds;               // [352][40]
  unsigned short* Ol = lds + 14080;
  unsigned short* W2h = lds + 28160;      // [128][40]
  unsigned short* W2l = lds + 33280;
  float* ow = out + (size_t)w * N * DIM;
  const int swz = ((l31 >> 3) & 3) << 3;
  const bool act = (wv < 11);

  f32x16 acc[4];
#pragma unroll
  for (int s = 0; s < 4; ++s)
#pragma unroll
    for (int r = 0; r < 16; ++r) acc[s][r] = 0.f;

  for (int kc = 0; kc < 4; ++kc) {
    __syncthreads();
    // O staging: 2816 quad-groups
#pragma unroll
    for (int p = 0; p < 4; ++p) {
      int idx = tid + p * 768;
      if (idx < 2816) {
        int row = idx >> 3, g = (idx & 7) << 2;
        float4v v = {0.f, 0.f, 0.f, 0.f};
        if (row < N) v = *(const float4v*)(ow + row * DIM + kc * 32 + g);
        unsigned h0, l0, h1, l1;
        split2pk(v[0], v[1], h0, l0);
        split2pk(v[2], v[3], h1, l1);
        uint2v hv = {h0, h1}, lv = {l0, l1};
        int gs = g ^ (((row >> 3) & 3) << 3);
        *(uint2v*)&Oh[row * 40 + gs] = hv;
        *(uint2v*)&Ol[row * 40 + gs] = lv;
      }
    }
    // W2 staging: 1024 quad-jobs (float4 along n, transposed scalar writes)
#pragma unroll
    for (int p = 0; p < 2; ++p) {
      int idx = tid + p * 768;
      if (idx < 1024) {
        int k = idx >> 5, n4 = (idx & 31) << 2;
        float4v v = *(const float4v*)(wout + (size_t)(kc * 32 + k) * DIM + n4);
#pragma unroll
        for (int u = 0; u < 4; ++u) {
          int n = n4 + u;
          int ks = k ^ (((n >> 3) & 3) << 3);
          unsigned short hv = bf16u(v[u]);
          W2h[n * 40 + ks] = hv;
          W2l[n * 40 + ks] =
              bf16u(v[u] - __builtin_bit_cast(float, (unsigned)hv << 16));
        }
      }
    }
    __syncthreads();
    if (act) {
#pragma unroll
      for (int kk = 0; kk < 2; ++kk) {
        int ro = (kk * 16 + half * 8) ^ swz;
        int rb = (wv * 32 + l31) * 40 + ro;
        short8 ah = *(const short8*)&Oh[rb];
        short8 al = *(const short8*)&Ol[rb];
#pragma unroll
        for (int s = 0; s < 4; ++s) {
          int wb = (s * 32 + l31) * 40 + ro;
          short8 bh = *(const short8*)&W2h[wb];
          short8 bl = *(const short8*)&W2l[wb];
          acc[s] = MFMA(ah, bh, acc[s], 0, 0, 0);
          acc[s] = MFMA(ah, bl, acc[s], 0, 0, 0);
          acc[s] = MFMA(al, bh, acc[s], 0, 0, 0);
        }
      }
    }
  }
  if (act) {
#pragma unroll
    for (int s = 0; s < 4; ++s) {
#pragma unroll
      for (int r = 0; r < 16; ++r) {
        int iD = (r & 3) + ((r >> 2) << 3) + (half << 2);
        int i = wv * 32 + iD;
        if (i < N) ow[(size_t)i * DIM + s * 32 + l31] = acc[s][r];
      }
    }
  }
}

// ---------------------------------------------------------------------------
extern "C" void kernel_launch(void* const* d_in, const int* in_sizes, int n_in,
                              void* d_out, int out_size, void* d_ws, size_t ws_size,
                              hipStream_t stream) {
  const float* x     = (const float*)d_in[0];
  const float* wqkv  = (const float*)d_in[1];
  const float* wout  = (const float*)d_in[2];
  const float* table = (const float*)d_in[3];
  const int*   rel   = (const int*)d_in[4];
  float* out  = (float*)d_out;
  float* prep = (float*)d_ws;  // 4*11*2*352*16*4 B = 1.98 MB

  const int B = in_sizes[0] / (N * DIM);  // 512 windows
  const int rows = HEADS * 11 * 2 * NP;   // 30976

  bias_kernel<<<(rows + 255) / 256, 256, 0, stream>>>(table, rel, prep);
  attn_kernel<<<HEADS * B, 768, 0, stream>>>(x, wqkv, prep, out);
  proj_kernel<<<B, 768, 0, stream>>>(wout, out);
}